// Round 13
// baseline (142.446 us; speedup 1.0000x reference)
//
#include <hip/hip_runtime.h>
#include <hip/hip_bf16.h>

#define B_ 4
#define N_ 4096
#define C_ 256
#define D_ 32
#define LOG2E 1.44269504088896340736f
#define MFMA16 __builtin_amdgcn_mfma_f32_16x16x32_bf16

typedef __attribute__((ext_vector_type(8))) short short8;   // 8 x bf16 (4 VGPRs)
typedef __attribute__((ext_vector_type(4))) short short4v;  // 4 x bf16 (8 B)
typedef __attribute__((ext_vector_type(4))) float float4v;  // MFMA C/D frag

// cheap round-to-nearest-even fp32->bf16 (finite inputs only): 3 VALU ops
__device__ inline short f2bf_rne(float f) {
  unsigned u = __builtin_bit_cast(unsigned, f);
  u += 0x7FFFu + ((u >> 16) & 1u);
  return (short)(u >> 16);
}
__device__ inline float bf2f(short s) {
  unsigned u = ((unsigned)(unsigned short)s) << 16;
  return __builtin_bit_cast(float, u);
}
__device__ inline float fast_exp2(float x) { return __builtin_amdgcn_exp2f(x); }

// gfx950 v_cvt_pk_bf16_f32: 2 fp32 -> 2 bf16 (RNE) in ONE VALU op.
__device__ inline short4v pk4_bf16(float p0, float p1, float p2, float p3) {
  union { unsigned u[2]; short4v s; } r;
  asm("v_cvt_pk_bf16_f32 %0, %1, %2" : "=v"(r.u[0]) : "v"(p0), "v"(p1));
  asm("v_cvt_pk_bf16_f32 %0, %1, %2" : "=v"(r.u[1]) : "v"(p2), "v"(p3));
  return r.s;
}

// ---------------------------------------------------------------------------
// Kernel 1: fragment-linearized bf16 weights WtF (unchanged).
// ---------------------------------------------------------------------------
__global__ __launch_bounds__(256) void cast_w_kernel(
    const float* __restrict__ Wq, const float* __restrict__ Wk,
    const float* __restrict__ Wv, short* __restrict__ WtF) {
  int i  = blockIdx.x * 256 + threadIdx.x;  // 0..81919
  int j  = i & 7;
  int l  = (i >> 3) & 63;
  int ks = (i >> 9) & 7;
  int nb = i >> 12;
  int n  = nb * 16 + (l & 15);
  int k  = ks * 32 + ((l >> 4) << 3) + j;
  float v;
  if (n < 32)      v = Wq[k * 32 + n] * LOG2E;
  else if (n < 64) v = Wk[k * 32 + (n - 32)];
  else             v = Wv[k * 256 + (n - 64)];
  WtF[i] = f2bf_rne(v);
}

// ---------------------------------------------------------------------------
// Kernel 2: fused QKV projection v3 (unchanged).
// ---------------------------------------------------------------------------
__global__ __launch_bounds__(256, 2) void proj_kernel(
    const float* __restrict__ x, const short* __restrict__ WtF,
    const float* __restrict__ bq, const float* __restrict__ bk,
    const float* __restrict__ bv,
    short* __restrict__ qb, short* __restrict__ kF, short* __restrict__ vF) {
  int blk = blockIdx.x;
  int b  = blk >> 7;
  int r0 = (blk & 127) * 32;
  int t  = threadIdx.x;
  int w  = t >> 6;
  int l  = t & 63;
  int lc = l & 15;
  int q4 = l >> 4;

  __shared__ __align__(16) short sA[32][272];  // 17.4 KB
  __shared__ __align__(16) short sV[256][40];  // 20.5 KB  [ch][row]
  __shared__ __align__(16) short sK[32][36];   // 2.3 KB   [row][d]

  {
    const float* xb = x + (size_t)(b * N_ + r0) * C_;
#pragma unroll
    for (int ch = 0; ch < 8; ch++) {
      int f   = ch * 256 + t;
      int row = f >> 6;
      int col = (f & 63) * 4;
      float4v v = *(const float4v*)(xb + f * 4);
      short4v s = pk4_bf16(v[0], v[1], v[2], v[3]);
      *(short4v*)(&sA[row][col]) = s;
    }
  }
  __syncthreads();

  float4v acc[10];  // [nbo*2 + rt]
#pragma unroll
  for (int i = 0; i < 10; i++) { acc[i][0] = 0.f; acc[i][1] = 0.f; acc[i][2] = 0.f; acc[i][3] = 0.f; }

  const short* wbase = WtF + w * 4096 + l * 8;  // frag(nbo,ks) at + nbo*16384 + ks*512

#define LOADW(B0, B1, B2, B3, B4, KS)                       \
  B0 = *(const short8*)(wbase + (KS) * 512 + 0 * 16384);    \
  B1 = *(const short8*)(wbase + (KS) * 512 + 1 * 16384);    \
  B2 = *(const short8*)(wbase + (KS) * 512 + 2 * 16384);    \
  B3 = *(const short8*)(wbase + (KS) * 512 + 3 * 16384);    \
  B4 = *(const short8*)(wbase + (KS) * 512 + 4 * 16384);

#define DO_MFMA(A0, A1, B0, B1, B2, B3, B4)                 \
  acc[0] = MFMA16(A0, B0, acc[0], 0, 0, 0);                 \
  acc[1] = MFMA16(A1, B0, acc[1], 0, 0, 0);                 \
  acc[2] = MFMA16(A0, B1, acc[2], 0, 0, 0);                 \
  acc[3] = MFMA16(A1, B1, acc[3], 0, 0, 0);                 \
  acc[4] = MFMA16(A0, B2, acc[4], 0, 0, 0);                 \
  acc[5] = MFMA16(A1, B2, acc[5], 0, 0, 0);                 \
  acc[6] = MFMA16(A0, B3, acc[6], 0, 0, 0);                 \
  acc[7] = MFMA16(A1, B3, acc[7], 0, 0, 0);                 \
  acc[8] = MFMA16(A0, B4, acc[8], 0, 0, 0);                 \
  acc[9] = MFMA16(A1, B4, acc[9], 0, 0, 0);

  short8 wA0, wA1, wA2, wA3, wA4, wB0, wB1, wB2, wB3, wB4;
  LOADW(wA0, wA1, wA2, wA3, wA4, 0)
#pragma unroll
  for (int kk = 0; kk < 8; kk += 2) {
    short8 a00 = *(const short8*)(&sA[lc][kk * 32 + q4 * 8]);
    short8 a01 = *(const short8*)(&sA[16 + lc][kk * 32 + q4 * 8]);
    LOADW(wB0, wB1, wB2, wB3, wB4, kk + 1)
    DO_MFMA(a00, a01, wA0, wA1, wA2, wA3, wA4)
    short8 a10 = *(const short8*)(&sA[lc][(kk + 1) * 32 + q4 * 8]);
    short8 a11 = *(const short8*)(&sA[16 + lc][(kk + 1) * 32 + q4 * 8]);
    LOADW(wA0, wA1, wA2, wA3, wA4, kk + 2)  // kk+2==8: harmless in-ws overread
    DO_MFMA(a10, a11, wB0, wB1, wB2, wB3, wB4)
  }
#undef LOADW
#undef DO_MFMA

  // epilogue: bias + cast; q scatter (tiny), k -> sK, v -> sV (b64 packed)
  {
    float bias0 = (w < 2) ? bq[w * 16 + lc] * LOG2E : bk[(w - 2) * 16 + lc];
#pragma unroll
    for (int rt = 0; rt < 2; rt++) {
      if (w < 2) {
#pragma unroll
        for (int r = 0; r < 4; r++) {
          int row = rt * 16 + q4 * 4 + r;
          qb[(size_t)(b * N_ + r0 + row) * D_ + w * 16 + lc] =
              f2bf_rne(acc[rt][r] + bias0);
        }
      } else {
#pragma unroll
        for (int r = 0; r < 4; r++) {
          int row = rt * 16 + q4 * 4 + r;
          sK[row][(w - 2) * 16 + lc] = f2bf_rne(acc[rt][r] + bias0);
        }
      }
    }
#pragma unroll
    for (int nbo = 1; nbo < 5; nbo++) {
      float bias = bv[(nbo - 1) * 64 + w * 16 + lc];
#pragma unroll
      for (int rt = 0; rt < 2; rt++) {
        float4v a = acc[nbo * 2 + rt];
        short4v pk = pk4_bf16(a[0] + bias, a[1] + bias, a[2] + bias, a[3] + bias);
        *(short4v*)(&sV[(nbo - 1) * 64 + w * 16 + lc][rt * 16 + q4 * 4]) = pk;
      }
    }
  }
  __syncthreads();

  int kt  = r0 >> 6;          // kv-tile these 32 rows belong to
  int ks0 = (r0 >> 5) & 1;    // which 32-kv half of the tile

  // vF writer: thread t writes 64 B CONTIGUOUS at tb2 + t*64B.
  {
    size_t tb2 = ((size_t)(b * 64 + kt) * 32 + ks0 * 16) * 512;
    int cb = t >> 4;
#pragma unroll
    for (int k = 0; k < 4; k++) {
      int p = (t & 15) * 4 + k;
      int j = p >> 4, i = p & 15;
      short8 vv = *(const short8*)(&sV[cb * 16 + i][j * 8]);
      *(short8*)(vF + tb2 + (size_t)t * 32 + k * 8) = vv;
    }
  }
  // kF writer: threads 0..127 write 16 B contiguous each.
  if (t < 128) {
    int fr = t >> 6, ll = t & 63;
    int kv = fr * 16 + (ll & 15), dg = ll >> 4;
    size_t tbk = ((size_t)(b * 64 + kt) * 4 + ks0 * 2) * 512;
    short8 kv8 = *(const short8*)(&sK[kv][dg * 8]);
    *(short8*)(kF + tbk + (size_t)t * 8) = kv8;
  }
}

// ---------------------------------------------------------------------------
// Kernel 3: flash FUSED v2 — R13: 32 q-rows per block (grid 512 = 2
// blocks/CU). R12's fusion won (-4us) but at grid 256 = 1 block/CU the
// per-tile cost rose 13% (Occupancy 18%, MfmaUtil 31%): no second block to
// overlap barrier drains. Halving the q-extent restores 2 blocks/CU with
// identical grid-wide MFMA count. Wave split: rq=w&1 (q 16-block),
// kh=(w>>1)&1 (kv 32-half), ks=w>>2 (kv 16-sub-block): each wave does ONE
// QK MFMA on K-frag kh*2+ks, writing its pack at fi*512 + ks*256 + slice
// (fi = rq*2+kh) — byte-generalization of the verified 64q address where
// S0/S1 <-> ks=0/1. PV: rt in {0,1}, 4 O accs, 8 MFMAs/tile/wave.
// l-reduction spans 4 waves per rq via sL2[8][16]. Epilogue unchanged.
// ---------------------------------------------------------------------------
__device__ __forceinline__ void barrier_lds_only() {
  asm volatile("s_waitcnt lgkmcnt(0)\n\ts_barrier" ::: "memory");
}

__global__ __launch_bounds__(512, 4) void flash_fused_kernel(
    const short* __restrict__ qb, const short* __restrict__ kF,
    const short* __restrict__ vF, const float* __restrict__ xin,
    const float* __restrict__ gptr, float* __restrict__ out) {
  int blk = blockIdx.x;        // 0..511
  int b  = blk & 3;            // XCD spread over batches for K/V L2 locality
  int qt = blk >> 2;           // 0..127
  int r0 = qt * 32;
  int t  = threadIdx.x;
  int w  = t >> 6;
  int l  = t & 63;
  int lc = l & 15;
  int q4 = l >> 4;
  int rq = w & 1;              // q 16-block owned by this wave (QK)
  int kh = (w >> 1) & 1;       // kv 32-half of the 64-kv tile (QK)
  int ks = w >> 2;             // kv 16-sub-block within the half (QK)

  __shared__ __align__(16) short sPn[2][2048];  // 8 KB: [buf][fi*512 + lane*8 + j]
  __shared__ float sL2[8][16];                  // per-wave l partials
  __shared__ float sLinv[32];                   // g / l per q-row

  float g = *gptr;

  // Q as B-frag (n=q, k=d); log2e pre-folded
  short8 qf = *(const short8*)(qb + (size_t)(b * N_ + r0 + rq * 16 + lc) * D_ + q4 * 8);

  // K: this wave's single frag (kh*2+ks) per tile; tile stride 2048 shorts
  const short* kbp = kF + ((size_t)(b * 64) * 4) * 512 + (kh * 2 + ks) * 512 + l * 8;
  // V: wave's 32-ch slice (gcb = 2w, 2w+1); tile stride 16384 shorts
  const short* vbp = vF + ((size_t)(b * 64) * 32 + 2 * w) * 512 + l * 8;

  short8 kC0;
  short8 vX00, vX01, vX10, vX11;
  short8 vY00, vY01, vY10, vY11;

  kC0 = *(const short8*)(kbp + 0);
  vX00 = *(const short8*)(vbp + 0);
  vX01 = *(const short8*)(vbp + 512);
  vX10 = *(const short8*)(vbp + 8192);
  vX11 = *(const short8*)(vbp + 8704);

  float4v O[4];  // [rt*2 + cbo]: 32 q x 32 ch
#pragma unroll
  for (int i = 0; i < 4; i++) { O[i][0] = 0.f; O[i][1] = 0.f; O[i][2] = 0.f; O[i][3] = 0.f; }
  float l_part = 0.f;

  // QK write base: frag fi = rq*2+kh, kv-16 sub-block ks at +ks*256.
  int qkbase = (rq * 2 + kh) * 512 + ks * 256 + (((q4 >> 1) * 16) + lc) * 8 + (q4 & 1) * 4;

#define K_RELOAD(TI)                                                           \
  { kC0 = *(const short8*)(kbp + (size_t)(TI) * 2048); }

#define QK_STEP(SPB, VALID)                                                    \
  { __builtin_amdgcn_s_setprio(1);                                             \
    float4v z; z[0] = 0.f; z[1] = 0.f; z[2] = 0.f; z[3] = 0.f;                 \
    float4v S0 = MFMA16(kC0, qf, z, 0, 0, 0);                                  \
    short* rowp = &sPn[SPB][qkbase];                                           \
    float p0 = fast_exp2(S0[0]), p1 = fast_exp2(S0[1]);                        \
    float p2 = fast_exp2(S0[2]), p3 = fast_exp2(S0[3]);                        \
    *(short4v*)(rowp) = pk4_bf16(p0, p1, p2, p3);                              \
    __builtin_amdgcn_s_setprio(0);                                             \
    if (VALID) l_part += (p0 + p1) + (p2 + p3); }

#define PV_STEP(SPB, V00, V01, V10, V11)                                       \
  { _Pragma("unroll")                                                          \
    for (int rt = 0; rt < 2; rt++) {                                           \
      short8 pf0 = *(const short8*)(&sPn[SPB][(rt * 2 + 0) * 512 + l * 8]);    \
      short8 pf1 = *(const short8*)(&sPn[SPB][(rt * 2 + 1) * 512 + l * 8]);    \
      O[rt * 2 + 0] = MFMA16(pf0, V00, O[rt * 2 + 0], 0, 0, 0);                \
      O[rt * 2 + 0] = MFMA16(pf1, V10, O[rt * 2 + 0], 0, 0, 0);                \
      O[rt * 2 + 1] = MFMA16(pf0, V01, O[rt * 2 + 1], 0, 0, 0);                \
      O[rt * 2 + 1] = MFMA16(pf1, V11, O[rt * 2 + 1], 0, 0, 0);                \
    } }

  QK_STEP(0, true)
  K_RELOAD(1)
  barrier_lds_only();

  for (int ti = 0; ti < 64; ti += 2) {
    int n1 = ti + 1;
    int n2 = (ti + 2 < 64) ? ti + 2 : 63;
    bool v2 = (ti + 2 < 64);
    int n3 = (ti + 3 < 64) ? ti + 3 : 63;

    { size_t vo = (size_t)n1 * 16384;
      vY00 = *(const short8*)(vbp + vo);
      vY01 = *(const short8*)(vbp + vo + 512);
      vY10 = *(const short8*)(vbp + vo + 8192);
      vY11 = *(const short8*)(vbp + vo + 8704); }
    QK_STEP(1, true)
    K_RELOAD(n2)
    PV_STEP(0, vX00, vX01, vX10, vX11)
    barrier_lds_only();

    { size_t vo = (size_t)n2 * 16384;
      vX00 = *(const short8*)(vbp + vo);
      vX01 = *(const short8*)(vbp + vo + 512);
      vX10 = *(const short8*)(vbp + vo + 8192);
      vX11 = *(const short8*)(vbp + vo + 8704); }
    QK_STEP(0, v2)
    K_RELOAD(n3)
    PV_STEP(1, vY00, vY01, vY10, vY11)
    barrier_lds_only();
  }
#undef K_RELOAD
#undef QK_STEP
#undef PV_STEP

  // ---- l reduction: intra-wave over q4 groups, then across 4 waves/rq ----
  {
    float l_tot = l_part + __shfl_xor(l_part, 16, 64);
    l_tot += __shfl_xor(l_tot, 32, 64);
    if (q4 == 0) sL2[w][lc] = l_tot;
    __syncthreads();
    if (w < 2 && q4 == 0) {
      float s = (sL2[w][lc] + sL2[w + 2][lc]) + (sL2[w + 4][lc] + sL2[w + 6][lc]);
      sLinv[w * 16 + lc] = g * __builtin_amdgcn_rcpf(s);
    }
    __syncthreads();
  }

  // ---- fused epilogue: out = O * (g/l) + x ----
  {
#pragma unroll
    for (int a = 0; a < 4; a++) {
      int rt   = a >> 1;
      int cbo  = a & 1;
      int row0 = rt * 16 + q4 * 4;
      int chg  = w * 32 + cbo * 16 + lc;
      size_t gi = (size_t)(b * N_ + r0 + row0) * C_ + chg;
      const float* xp = xin + gi;
      float* op = out + gi;
      float4v o = O[a];
#pragma unroll
      for (int r = 0; r < 4; r++) {
        op[(size_t)r * C_] = o[r] * sLinv[row0 + r] + xp[(size_t)r * C_];
      }
    }
  }
}

// ---------------------------------------------------------------------------
extern "C" void kernel_launch(void* const* d_in, const int* in_sizes, int n_in,
                              void* d_out, int out_size, void* d_ws, size_t ws_size,
                              hipStream_t stream) {
  const float* x     = (const float*)d_in[0];
  const float* Wq    = (const float*)d_in[1];
  const float* bq    = (const float*)d_in[2];
  const float* Wk    = (const float*)d_in[3];
  const float* bk    = (const float*)d_in[4];
  const float* Wv    = (const float*)d_in[5];
  const float* bv    = (const float*)d_in[6];
  const float* gamma = (const float*)d_in[7];
  float* out = (float*)d_out;

  char* ws = (char*)d_ws;
  short* qb   = (short*)ws;                   // 1 MB   row-major [N][32]
  short* kF   = (short*)(ws + (1u << 20));    // 1 MB   fragment-linear
  short* vF   = (short*)(ws + (2u << 20));    // 8 MB   fragment-linear
  short* WtF  = (short*)(ws + (10u << 20));   // 160 KB fragment-linear

  hipLaunchKernelGGL(cast_w_kernel,      dim3(320), dim3(256), 0, stream, Wq, Wk, Wv, WtF);
  hipLaunchKernelGGL(proj_kernel,        dim3(512), dim3(256), 0, stream, x, WtF, bq, bk, bv, qb, kF, vF);
  hipLaunchKernelGGL(flash_fused_kernel, dim3(512), dim3(512), 0, stream, qb, kF, vF, x, gamma, out);
}

// Round 14
// 133.248 us; speedup vs baseline: 1.0690x; 1.0690x over previous
//
#include <hip/hip_runtime.h>
#include <hip/hip_bf16.h>

#define B_ 4
#define N_ 4096
#define C_ 256
#define D_ 32
#define LOG2E 1.44269504088896340736f
#define MFMA16 __builtin_amdgcn_mfma_f32_16x16x32_bf16

typedef __attribute__((ext_vector_type(8))) short short8;   // 8 x bf16 (4 VGPRs)
typedef __attribute__((ext_vector_type(4))) short short4v;  // 4 x bf16 (8 B)
typedef __attribute__((ext_vector_type(4))) float float4v;  // MFMA C/D frag

// cheap round-to-nearest-even fp32->bf16 (finite inputs only): 3 VALU ops
__device__ inline short f2bf_rne(float f) {
  unsigned u = __builtin_bit_cast(unsigned, f);
  u += 0x7FFFu + ((u >> 16) & 1u);
  return (short)(u >> 16);
}
__device__ inline float bf2f(short s) {
  unsigned u = ((unsigned)(unsigned short)s) << 16;
  return __builtin_bit_cast(float, u);
}
__device__ inline float fast_exp2(float x) { return __builtin_amdgcn_exp2f(x); }

// gfx950 v_cvt_pk_bf16_f32: 2 fp32 -> 2 bf16 (RNE) in ONE VALU op.
__device__ inline short4v pk4_bf16(float p0, float p1, float p2, float p3) {
  union { unsigned u[2]; short4v s; } r;
  asm("v_cvt_pk_bf16_f32 %0, %1, %2" : "=v"(r.u[0]) : "v"(p0), "v"(p1));
  asm("v_cvt_pk_bf16_f32 %0, %1, %2" : "=v"(r.u[1]) : "v"(p2), "v"(p3));
  return r.s;
}

// ---------------------------------------------------------------------------
// Kernel 1: fragment-linearized bf16 weights WtF (unchanged).
// ---------------------------------------------------------------------------
__global__ __launch_bounds__(256) void cast_w_kernel(
    const float* __restrict__ Wq, const float* __restrict__ Wk,
    const float* __restrict__ Wv, short* __restrict__ WtF) {
  int i  = blockIdx.x * 256 + threadIdx.x;  // 0..81919
  int j  = i & 7;
  int l  = (i >> 3) & 63;
  int ks = (i >> 9) & 7;
  int nb = i >> 12;
  int n  = nb * 16 + (l & 15);
  int k  = ks * 32 + ((l >> 4) << 3) + j;
  float v;
  if (n < 32)      v = Wq[k * 32 + n] * LOG2E;
  else if (n < 64) v = Wk[k * 32 + (n - 32)];
  else             v = Wv[k * 256 + (n - 64)];
  WtF[i] = f2bf_rne(v);
}

// ---------------------------------------------------------------------------
// Kernel 2: fused QKV projection v3 (unchanged).
// ---------------------------------------------------------------------------
__global__ __launch_bounds__(256, 2) void proj_kernel(
    const float* __restrict__ x, const short* __restrict__ WtF,
    const float* __restrict__ bq, const float* __restrict__ bk,
    const float* __restrict__ bv,
    short* __restrict__ qb, short* __restrict__ kF, short* __restrict__ vF) {
  int blk = blockIdx.x;
  int b  = blk >> 7;
  int r0 = (blk & 127) * 32;
  int t  = threadIdx.x;
  int w  = t >> 6;
  int l  = t & 63;
  int lc = l & 15;
  int q4 = l >> 4;

  __shared__ __align__(16) short sA[32][272];  // 17.4 KB
  __shared__ __align__(16) short sV[256][40];  // 20.5 KB  [ch][row]
  __shared__ __align__(16) short sK[32][36];   // 2.3 KB   [row][d]

  {
    const float* xb = x + (size_t)(b * N_ + r0) * C_;
#pragma unroll
    for (int ch = 0; ch < 8; ch++) {
      int f   = ch * 256 + t;
      int row = f >> 6;
      int col = (f & 63) * 4;
      float4v v = *(const float4v*)(xb + f * 4);
      short4v s = pk4_bf16(v[0], v[1], v[2], v[3]);
      *(short4v*)(&sA[row][col]) = s;
    }
  }
  __syncthreads();

  float4v acc[10];  // [nbo*2 + rt]
#pragma unroll
  for (int i = 0; i < 10; i++) { acc[i][0] = 0.f; acc[i][1] = 0.f; acc[i][2] = 0.f; acc[i][3] = 0.f; }

  const short* wbase = WtF + w * 4096 + l * 8;  // frag(nbo,ks) at + nbo*16384 + ks*512

#define LOADW(B0, B1, B2, B3, B4, KS)                       \
  B0 = *(const short8*)(wbase + (KS) * 512 + 0 * 16384);    \
  B1 = *(const short8*)(wbase + (KS) * 512 + 1 * 16384);    \
  B2 = *(const short8*)(wbase + (KS) * 512 + 2 * 16384);    \
  B3 = *(const short8*)(wbase + (KS) * 512 + 3 * 16384);    \
  B4 = *(const short8*)(wbase + (KS) * 512 + 4 * 16384);

#define DO_MFMA(A0, A1, B0, B1, B2, B3, B4)                 \
  acc[0] = MFMA16(A0, B0, acc[0], 0, 0, 0);                 \
  acc[1] = MFMA16(A1, B0, acc[1], 0, 0, 0);                 \
  acc[2] = MFMA16(A0, B1, acc[2], 0, 0, 0);                 \
  acc[3] = MFMA16(A1, B1, acc[3], 0, 0, 0);                 \
  acc[4] = MFMA16(A0, B2, acc[4], 0, 0, 0);                 \
  acc[5] = MFMA16(A1, B2, acc[5], 0, 0, 0);                 \
  acc[6] = MFMA16(A0, B3, acc[6], 0, 0, 0);                 \
  acc[7] = MFMA16(A1, B3, acc[7], 0, 0, 0);                 \
  acc[8] = MFMA16(A0, B4, acc[8], 0, 0, 0);                 \
  acc[9] = MFMA16(A1, B4, acc[9], 0, 0, 0);

  short8 wA0, wA1, wA2, wA3, wA4, wB0, wB1, wB2, wB3, wB4;
  LOADW(wA0, wA1, wA2, wA3, wA4, 0)
#pragma unroll
  for (int kk = 0; kk < 8; kk += 2) {
    short8 a00 = *(const short8*)(&sA[lc][kk * 32 + q4 * 8]);
    short8 a01 = *(const short8*)(&sA[16 + lc][kk * 32 + q4 * 8]);
    LOADW(wB0, wB1, wB2, wB3, wB4, kk + 1)
    DO_MFMA(a00, a01, wA0, wA1, wA2, wA3, wA4)
    short8 a10 = *(const short8*)(&sA[lc][(kk + 1) * 32 + q4 * 8]);
    short8 a11 = *(const short8*)(&sA[16 + lc][(kk + 1) * 32 + q4 * 8]);
    LOADW(wA0, wA1, wA2, wA3, wA4, kk + 2)  // kk+2==8: harmless in-ws overread
    DO_MFMA(a10, a11, wB0, wB1, wB2, wB3, wB4)
  }
#undef LOADW
#undef DO_MFMA

  // epilogue: bias + cast; q scatter (tiny), k -> sK, v -> sV (b64 packed)
  {
    float bias0 = (w < 2) ? bq[w * 16 + lc] * LOG2E : bk[(w - 2) * 16 + lc];
#pragma unroll
    for (int rt = 0; rt < 2; rt++) {
      if (w < 2) {
#pragma unroll
        for (int r = 0; r < 4; r++) {
          int row = rt * 16 + q4 * 4 + r;
          qb[(size_t)(b * N_ + r0 + row) * D_ + w * 16 + lc] =
              f2bf_rne(acc[rt][r] + bias0);
        }
      } else {
#pragma unroll
        for (int r = 0; r < 4; r++) {
          int row = rt * 16 + q4 * 4 + r;
          sK[row][(w - 2) * 16 + lc] = f2bf_rne(acc[rt][r] + bias0);
        }
      }
    }
#pragma unroll
    for (int nbo = 1; nbo < 5; nbo++) {
      float bias = bv[(nbo - 1) * 64 + w * 16 + lc];
#pragma unroll
      for (int rt = 0; rt < 2; rt++) {
        float4v a = acc[nbo * 2 + rt];
        short4v pk = pk4_bf16(a[0] + bias, a[1] + bias, a[2] + bias, a[3] + bias);
        *(short4v*)(&sV[(nbo - 1) * 64 + w * 16 + lc][rt * 16 + q4 * 4]) = pk;
      }
    }
  }
  __syncthreads();

  int kt  = r0 >> 6;          // kv-tile these 32 rows belong to
  int ks0 = (r0 >> 5) & 1;    // which 32-kv half of the tile

  // vF writer: thread t writes 64 B CONTIGUOUS at tb2 + t*64B.
  {
    size_t tb2 = ((size_t)(b * 64 + kt) * 32 + ks0 * 16) * 512;
    int cb = t >> 4;
#pragma unroll
    for (int k = 0; k < 4; k++) {
      int p = (t & 15) * 4 + k;
      int j = p >> 4, i = p & 15;
      short8 vv = *(const short8*)(&sV[cb * 16 + i][j * 8]);
      *(short8*)(vF + tb2 + (size_t)t * 32 + k * 8) = vv;
    }
  }
  // kF writer: threads 0..127 write 16 B contiguous each.
  if (t < 128) {
    int fr = t >> 6, ll = t & 63;
    int kv = fr * 16 + (ll & 15), dg = ll >> 4;
    size_t tbk = ((size_t)(b * 64 + kt) * 4 + ks0 * 2) * 512;
    short8 kv8 = *(const short8*)(&sK[kv][dg * 8]);
    *(short8*)(kF + tbk + (size_t)t * 8) = kv8;
  }
}

// ---------------------------------------------------------------------------
// Kernel 3: flash FUSED — the VERIFIED session best (R12, 131.2us total).
// Each block scans the FULL 4096-kv range (64 tiles; grid 256), so l and O
// complete in-block and the merge kernel is deleted; normalize+gamma+residual
// fused as epilogue: out = O*(g/l) + x. Main loop = verified R8 structure
// (symmetric 8-wave QK split, lgkmcnt-only barriers — no vmcnt drain).
// Family mapped this session: R8 (64q,kv/2,+merge)=135.3; THIS=131.2;
// R13 (32q,full-kv, 2 blk/CU)=142.4 (barrier cost amortized over half the
// per-interval work — intervals/CU, not occupancy, is the currency).
// Rejected levers: wave rebalance, 4 blk/CU, P-reg preload, de-phase,
// zero-barrier bpermute-P (2.5x worse), deep pipelines (NaN x2).
// ---------------------------------------------------------------------------
__device__ __forceinline__ void barrier_lds_only() {
  asm volatile("s_waitcnt lgkmcnt(0)\n\ts_barrier" ::: "memory");
}

__global__ __launch_bounds__(512, 4) void flash_fused_kernel(
    const short* __restrict__ qb, const short* __restrict__ kF,
    const short* __restrict__ vF, const float* __restrict__ xin,
    const float* __restrict__ gptr, float* __restrict__ out) {
  int blk = blockIdx.x;        // 0..255
  int b  = blk & 3;            // XCD x serves batch x&3 only: K/V L2-resident
  int qt = blk >> 2;           // 0..63
  int r0 = qt * 64;
  int t  = threadIdx.x;
  int w  = t >> 6;
  int l  = t & 63;
  int lc = l & 15;
  int q4 = l >> 4;
  int rq = w & 3;              // q 16-block owned by this wave (QK)
  int kh = w >> 2;             // kv 32-half of the 64-kv tile owned (QK)

  __shared__ __align__(16) short sPn[2][4096];  // 16 KB: [buf][fi*512 + lane*8 + j]
  __shared__ float sL[4][16];                   // cross-wave l reduction scratch
  __shared__ float sLinv[64];                   // g / l per q-row

  float g = *gptr;

  // Q as B-frag (n=q, k=d); log2e pre-folded
  short8 qf = *(const short8*)(qb + (size_t)(b * N_ + r0 + rq * 16 + lc) * D_ + q4 * 8);

  // K/V bases: full batch kv range (64 tiles)
  const short* kbp = kF + ((size_t)(b * 64) * 4) * 512 + kh * 1024 + l * 8;
  const short* vbp = vF + ((size_t)(b * 64) * 32 + 2 * w) * 512 + l * 8;

  short8 kC0, kC1;
  short8 vX00, vX01, vX10, vX11;
  short8 vY00, vY01, vY10, vY11;

  kC0 = *(const short8*)(kbp + 0);
  kC1 = *(const short8*)(kbp + 512);
  vX00 = *(const short8*)(vbp + 0);
  vX01 = *(const short8*)(vbp + 512);
  vX10 = *(const short8*)(vbp + 8192);
  vX11 = *(const short8*)(vbp + 8704);

  float4v O[8];  // [rt*2 + cbo]: 64 q x 32 ch
#pragma unroll
  for (int i = 0; i < 8; i++) { O[i][0] = 0.f; O[i][1] = 0.f; O[i][2] = 0.f; O[i][3] = 0.f; }
  float l_part = 0.f;

  // QK write base within a buf: kv 16-block i of this tile lands at
  // qkbase + i*256 shorts; this wave owns i = 2*kh and 2*kh+1.
  int qkbase = (rq * 2) * 512 + (((q4 >> 1) * 16) + lc) * 8 + (q4 & 1) * 4;

#define K_RELOAD(TI)                                                           \
  { size_t o_ = (size_t)(TI) * 2048;                                           \
    kC0 = *(const short8*)(kbp + o_);                                          \
    kC1 = *(const short8*)(kbp + o_ + 512); }

#define QK_STEP(SPB, VALID)                                                    \
  { __builtin_amdgcn_s_setprio(1);                                             \
    float4v z; z[0] = 0.f; z[1] = 0.f; z[2] = 0.f; z[3] = 0.f;                 \
    float4v S0 = MFMA16(kC0, qf, z, 0, 0, 0);                                  \
    float4v S1 = MFMA16(kC1, qf, z, 0, 0, 0);                                  \
    short* rowp = &sPn[SPB][qkbase + kh * 512];                                \
    float ts = 0.f;                                                            \
    { float p0 = fast_exp2(S0[0]), p1 = fast_exp2(S0[1]);                      \
      float p2 = fast_exp2(S0[2]), p3 = fast_exp2(S0[3]);                      \
      ts += (p0 + p1) + (p2 + p3);                                             \
      *(short4v*)(rowp + 0) = pk4_bf16(p0, p1, p2, p3); }                      \
    { float p0 = fast_exp2(S1[0]), p1 = fast_exp2(S1[1]);                      \
      float p2 = fast_exp2(S1[2]), p3 = fast_exp2(S1[3]);                      \
      ts += (p0 + p1) + (p2 + p3);                                             \
      *(short4v*)(rowp + 256) = pk4_bf16(p0, p1, p2, p3); }                    \
    __builtin_amdgcn_s_setprio(0);                                             \
    if (VALID) l_part += ts; }

#define PV_STEP(SPB, V00, V01, V10, V11)                                       \
  { _Pragma("unroll")                                                          \
    for (int rt = 0; rt < 4; rt++) {                                           \
      short8 pf0 = *(const short8*)(&sPn[SPB][(rt * 2 + 0) * 512 + l * 8]);    \
      short8 pf1 = *(const short8*)(&sPn[SPB][(rt * 2 + 1) * 512 + l * 8]);    \
      O[rt * 2 + 0] = MFMA16(pf0, V00, O[rt * 2 + 0], 0, 0, 0);                \
      O[rt * 2 + 0] = MFMA16(pf1, V10, O[rt * 2 + 0], 0, 0, 0);                \
      O[rt * 2 + 1] = MFMA16(pf0, V01, O[rt * 2 + 1], 0, 0, 0);                \
      O[rt * 2 + 1] = MFMA16(pf1, V11, O[rt * 2 + 1], 0, 0, 0);                \
    } }

  QK_STEP(0, true)
  K_RELOAD(1)
  barrier_lds_only();

  for (int ti = 0; ti < 64; ti += 2) {
    int n1 = ti + 1;
    int n2 = (ti + 2 < 64) ? ti + 2 : 63;
    bool v2 = (ti + 2 < 64);
    int n3 = (ti + 3 < 64) ? ti + 3 : 63;

    { size_t vo = (size_t)n1 * 16384;
      vY00 = *(const short8*)(vbp + vo);
      vY01 = *(const short8*)(vbp + vo + 512);
      vY10 = *(const short8*)(vbp + vo + 8192);
      vY11 = *(const short8*)(vbp + vo + 8704); }
    QK_STEP(1, true)
    K_RELOAD(n2)
    PV_STEP(0, vX00, vX01, vX10, vX11)
    barrier_lds_only();

    { size_t vo = (size_t)n2 * 16384;
      vX00 = *(const short8*)(vbp + vo);
      vX01 = *(const short8*)(vbp + vo + 512);
      vX10 = *(const short8*)(vbp + vo + 8192);
      vX11 = *(const short8*)(vbp + vo + 8704); }
    QK_STEP(0, v2)
    K_RELOAD(n3)
    PV_STEP(1, vY00, vY01, vY10, vY11)
    barrier_lds_only();
  }
#undef K_RELOAD
#undef QK_STEP
#undef PV_STEP

  // ---- l reduction (full kv in-block): quad groups, then kh pair ----
  {
    float l_tot = l_part + __shfl_xor(l_part, 16, 64);
    l_tot += __shfl_xor(l_tot, 32, 64);
    if (kh == 0 && q4 == 0) sL[rq][lc] = l_tot;
    __syncthreads();
    if (kh == 1 && q4 == 0)
      sLinv[rq * 16 + lc] = g * __builtin_amdgcn_rcpf(l_tot + sL[rq][lc]);
    __syncthreads();
  }

  // ---- fused epilogue: out = O * (g/l) + x (merge semantics, in-block) ----
  {
#pragma unroll
    for (int a = 0; a < 8; a++) {
      int rt   = a >> 1;
      int cbo  = a & 1;
      int row0 = rt * 16 + q4 * 4;
      int chg  = w * 32 + cbo * 16 + lc;
      size_t gi = (size_t)(b * N_ + r0 + row0) * C_ + chg;
      const float* xp = xin + gi;
      float* op = out + gi;
      float4v o = O[a];
#pragma unroll
      for (int r = 0; r < 4; r++) {
        op[(size_t)r * C_] = o[r] * sLinv[row0 + r] + xp[(size_t)r * C_];
      }
    }
  }
}

// ---------------------------------------------------------------------------
extern "C" void kernel_launch(void* const* d_in, const int* in_sizes, int n_in,
                              void* d_out, int out_size, void* d_ws, size_t ws_size,
                              hipStream_t stream) {
  const float* x     = (const float*)d_in[0];
  const float* Wq    = (const float*)d_in[1];
  const float* bq    = (const float*)d_in[2];
  const float* Wk    = (const float*)d_in[3];
  const float* bk    = (const float*)d_in[4];
  const float* Wv    = (const float*)d_in[5];
  const float* bv    = (const float*)d_in[6];
  const float* gamma = (const float*)d_in[7];
  float* out = (float*)d_out;

  char* ws = (char*)d_ws;
  short* qb   = (short*)ws;                   // 1 MB   row-major [N][32]
  short* kF   = (short*)(ws + (1u << 20));    // 1 MB   fragment-linear
  short* vF   = (short*)(ws + (2u << 20));    // 8 MB   fragment-linear
  short* WtF  = (short*)(ws + (10u << 20));   // 160 KB fragment-linear

  hipLaunchKernelGGL(cast_w_kernel,      dim3(320), dim3(256), 0, stream, Wq, Wk, Wv, WtF);
  hipLaunchKernelGGL(proj_kernel,        dim3(512), dim3(256), 0, stream, x, WtF, bq, bk, bv, qb, kF, vF);
  hipLaunchKernelGGL(flash_fused_kernel, dim3(256), dim3(512), 0, stream, qb, kF, vF, x, gamma, out);
}